// Round 1
// 675.287 us; speedup vs baseline: 1.0683x; 1.0683x over previous
//
#include <hip/hip_runtime.h>
#include <hip/hip_bf16.h>
#include <stdint.h>

#define HIDDEN 2048
#define BATCH 16384
#define NUM_OPS 3
#define NT_M 67                 // 256-row m-tiles: 16384 + 3*255 pad <= 17152
#define M_CAP (NT_M * 256)      // 17152
#define NXT 8                   // 256-wide n-tiles (2048/256)
#define KT 32                   // K-tiles of 64 (2048/64)

typedef __attribute__((ext_vector_type(4))) float f32x4;
typedef __attribute__((ext_vector_type(8))) short short8;
typedef __attribute__((ext_vector_type(8))) __bf16 bf16x8;

// ---- workspace layout (bytes) ----
static constexpr size_t XB_SZ   = (size_t)M_CAP * HIDDEN * 2;            // sorted x, bf16
static constexpr size_t H_SZ    = XB_SZ;                                 // hidden, bf16
static constexpr size_t WT_SZ   = (size_t)NUM_OPS * HIDDEN * HIDDEN * 2; // transposed bf16 weights
static constexpr size_t PERM_SZ = (size_t)M_CAP * 4;

__device__ __forceinline__ unsigned f2bf(float f) {
  unsigned u = __float_as_uint(f);
  return (u + 0x7FFFu + ((u >> 16) & 1u)) >> 16;   // RNE
}

__device__ __forceinline__ void async_ld16(const void* g, void* l) {
  __builtin_amdgcn_global_load_lds(
      (__attribute__((address_space(1))) void*)(void*)g,
      (__attribute__((address_space(3))) void*)l, 16, 0, 0);
}

// ---- partition kernels (ballot-aggregated atomics) ----
__global__ __launch_bounds__(256) void k_count(const int* __restrict__ ops,
                                               int* __restrict__ cnt,
                                               int* __restrict__ perm) {
  int i = blockIdx.x * 256 + threadIdx.x;
  if (i < M_CAP) perm[i] = -1;
  int e = (i < BATCH) ? ops[i] : -1;
  int lane = threadIdx.x & 63;
#pragma unroll
  for (int ee = 0; ee < NUM_OPS; ee++) {
    unsigned long long m = __ballot(e == ee);
    if (lane == 0 && m) atomicAdd(&cnt[ee], __popcll(m));
  }
}

__global__ void k_scan(const int* __restrict__ cnt, int* __restrict__ seg,
                       int* __restrict__ te) {
  int a0 = (cnt[0] + 255) & ~255;
  int a1 = (cnt[1] + 255) & ~255;
  int a2 = (cnt[2] + 255) & ~255;
  if (threadIdx.x == 0) {
    seg[0] = 0; seg[1] = a0; seg[2] = a0 + a1; seg[3] = a0 + a1 + a2;
  }
  for (int t = threadIdx.x; t < NT_M; t += 64) {
    int row = t * 256;
    int ex = -1;
    if (row < a0) ex = 0;
    else if (row < a0 + a1) ex = 1;
    else if (row < a0 + a1 + a2) ex = 2;
    te[t] = ex;
  }
}

__global__ __launch_bounds__(256) void k_perm(const int* __restrict__ ops,
                                              const int* __restrict__ seg,
                                              int* __restrict__ c2,
                                              int* __restrict__ perm) {
  int b = blockIdx.x * 256 + threadIdx.x;
  int e = (b < BATCH) ? ops[b] : -1;
  int lane = threadIdx.x & 63;
#pragma unroll
  for (int ee = 0; ee < NUM_OPS; ee++) {
    unsigned long long m = __ballot(e == ee);
    if (m) {
      int base = 0;
      if (lane == 0) base = atomicAdd(&c2[ee], __popcll(m));
      base = __shfl(base, 0);
      if (e == ee) {
        int myoff = __popcll(m & ((1ull << lane) - 1ull));
        perm[seg[ee] + base + myoff] = b;
      }
    }
  }
}

// ---- fused prep: gather+convert x and W[e][k][n] -> Wt[e][n][k] bf16 ----
__global__ __launch_bounds__(256) void k_prep(const float* __restrict__ x,
                                              const int* __restrict__ perm,
                                              short* __restrict__ xb,
                                              const float* __restrict__ W1,
                                              const float* __restrict__ W2,
                                              short* __restrict__ W1t,
                                              short* __restrict__ W2t) {
  int tid = threadIdx.x;
  if (blockIdx.x < M_CAP) {
    int pos = blockIdx.x;
    int b = perm[pos];
    uint4 o;
    if (b < 0) {
      o = make_uint4(0u, 0u, 0u, 0u);
    } else {
      const float4* xs = (const float4*)(x + (size_t)b * HIDDEN + tid * 8);
      float4 f0 = xs[0], f1 = xs[1];
      o.x = f2bf(f0.x) | (f2bf(f0.y) << 16);
      o.y = f2bf(f0.z) | (f2bf(f0.w) << 16);
      o.z = f2bf(f1.x) | (f2bf(f1.y) << 16);
      o.w = f2bf(f1.z) | (f2bf(f1.w) << 16);
    }
    *(uint4*)(xb + (size_t)pos * HIDDEN + tid * 8) = o;
  } else {
    __shared__ float t[64][65];
    int q = blockIdx.x - M_CAP;     // 0..6143
    int z = q >> 10;                // 0..5: expert*layer
    int rem = q & 1023;
    int by = rem >> 5, bx = rem & 31;
    const float* src = (z < 3) ? (W1 + (size_t)z * HIDDEN * HIDDEN)
                               : (W2 + (size_t)(z - 3) * HIDDEN * HIDDEN);
    short* dst = (z < 3) ? (W1t + (size_t)z * HIDDEN * HIDDEN)
                         : (W2t + (size_t)(z - 3) * HIDDEN * HIDDEN);
    int k0 = by * 64;
    int n0 = bx * 64;
    {
      int kk = tid >> 4, n4 = (tid & 15) * 4;
#pragma unroll
      for (int p = 0; p < 4; p++) {
        int k = p * 16 + kk;
        *(float4*)&t[k][n4] = *(const float4*)&src[(size_t)(k0 + k) * HIDDEN + n0 + n4];
      }
    }
    __syncthreads();
#pragma unroll
    for (int p = 0; p < 2; p++) {
      int qq = p * 256 + tid;
      int n = qq >> 3, uc = qq & 7;
      uint4 o;
      unsigned* po = (unsigned*)&o;
#pragma unroll
      for (int j = 0; j < 4; j++) {
        float a = t[uc * 8 + 2 * j][n];
        float c = t[uc * 8 + 2 * j + 1][n];
        po[j] = f2bf(a) | (f2bf(c) << 16);
      }
      *(uint4*)&dst[(size_t)(n0 + n) * HIDDEN + k0 + uc * 8] = o;
    }
  }
}

// ---- 256x256 8-phase bf16 GEMM (T2+T3+T4+T5), BK=64, 8 waves (2Mx4N) ----
// LDS 128 KiB: per buf {A[2 halves of 128x64], B[2 halves of 128x64]}, XOR-
// swizzled via pre-swizzled global source + swizzled ds_read (involution).
// Per K-tile: 4 phases; stage A(t+1) at P1/P2 (into buf^1), B(t+2) at P3/P4
// (into current buf's B region: all B reads done by end of P2). Single
// s_waitcnt vmcnt(4) per K-tile (2 half-tiles stay in flight), vmcnt(0)
// only in the epilogue drain.
template <int SECOND>
__global__ __launch_bounds__(512, 2)
void gemm256(const short* __restrict__ A, const short* __restrict__ Wt,
             const float* __restrict__ bias, const int* __restrict__ te,
             const int* __restrict__ perm, short* __restrict__ Hout,
             float* __restrict__ Yout) {
  extern __shared__ short lds[];   // 65536 shorts = 128 KiB

  const int lin = blockIdx.x;
  const int xt = lin & 7;          // n-tile == XCD affinity
  const int yt = lin >> 3;         // m-tile
  const int e = te[yt];
  if (e < 0) return;

  const int tid = threadIdx.x;
  const int wid = tid >> 6;
  const int lane = tid & 63;
  const int quad = lane >> 4;
  const int l16 = lane & 15;
  const int wmh = wid >> 2;            // 0/1: which A half this wave consumes
  const int wnq = wid & 3;             // 0..3: 64-col B slice
  const int brow0 = (wnq & 1) * 64;    // row offset within the B half

  const short* Ag = A + (size_t)yt * 256 * HIDDEN;
  const short* Bg = Wt + (size_t)e * HIDDEN * HIDDEN + (size_t)xt * 256 * HIDDEN;

  // staging: chunk idx = i*512+tid -> LDS slot (r=idx>>3, c7=idx&7);
  // source column chunk = c7 ^ (r&7)  (pre-swizzled source, rule 21)
  const int r0 = tid >> 3;
  const int c0 = ((tid & 7) ^ (r0 & 7)) * 8;
  const short* pA = Ag + (size_t)r0 * HIDDEN + c0;
  const short* pB = Bg + (size_t)r0 * HIDDEN + c0;
  const int dstw = wid * 512;          // wave-uniform LDS dest (shorts), +4096 for load 1

  auto stage = [&](const short* src, int dst) {
    async_ld16(src, lds + dst + dstw);
    async_ld16(src + 64 * HIDDEN, lds + dst + 4096 + dstw);
  };
  // swizzled fragment read: logical (row r, k-chunk q) of a 128x64 half
  auto frag = [&](int base, int r, int q) {
    return __builtin_bit_cast(bf16x8,
        *(const short8*)(lds + base + r * 64 + ((q ^ (r & 7)) * 8)));
  };

  f32x4 acc[8][4] = {};
  bf16x8 af[4][2], bA[2][2], bB[2][2];

  // ---- prologue: tile0 {Alo,Ahi,Blo,Bhi} -> buf0, tile1 {Blo,Bhi} -> buf1 ----
  stage(pA, 0);
  stage(pA + 128 * HIDDEN, 8192);
  stage(pB, 16384);
  stage(pB + 128 * HIDDEN, 24576);
  stage(pB + 64, 32768 + 16384);
  stage(pB + 64 + 128 * HIDDEN, 32768 + 24576);
  asm volatile("s_waitcnt vmcnt(4)" ::: "memory");   // tile0 landed; tile1 B in flight
  __builtin_amdgcn_s_barrier();

  for (int t = 0; t < KT; ++t) {
    const int b = (t & 1) << 15;                    // current buffer base (shorts)
    const int nb = 32768 - b;                       // other buffer base
    const int aMy = b + wmh * 8192;                 // my A half
    const int bMy = b + 16384 + (wnq >> 1) * 8192;  // my B half
    const short* pAn = pA + (t + 1) * 64;
    const short* pBn = pB + (t + 2) * 64;

    // ---------------- P1: quadrant (rows 0-3, cols 0-1) ----------------
#pragma unroll
    for (int i = 0; i < 4; ++i)
#pragma unroll
      for (int s = 0; s < 2; ++s)
        af[i][s] = frag(aMy, i * 16 + l16, s * 4 + quad);
#pragma unroll
    for (int j = 0; j < 2; ++j)
#pragma unroll
      for (int s = 0; s < 2; ++s)
        bA[j][s] = frag(bMy, brow0 + j * 16 + l16, s * 4 + quad);
    if (t + 1 < KT) stage(pAn, nb);                 // A(t+1) lo
    __builtin_amdgcn_sched_barrier(0);
    __builtin_amdgcn_s_barrier();
    asm volatile("s_waitcnt lgkmcnt(0)" ::: "memory");
    __builtin_amdgcn_sched_barrier(0);
    __builtin_amdgcn_s_setprio(1);
#pragma unroll
    for (int i = 0; i < 4; ++i)
#pragma unroll
      for (int j = 0; j < 2; ++j)
#pragma unroll
        for (int s = 0; s < 2; ++s)
          acc[i][j] = __builtin_amdgcn_mfma_f32_16x16x32_bf16(af[i][s], bA[j][s], acc[i][j], 0, 0, 0);
    __builtin_amdgcn_s_setprio(0);
    __builtin_amdgcn_sched_barrier(0);
    __builtin_amdgcn_s_barrier();

    // ---------------- P2: quadrant (rows 0-3, cols 2-3) ----------------
#pragma unroll
    for (int j = 0; j < 2; ++j)
#pragma unroll
      for (int s = 0; s < 2; ++s)
        bB[j][s] = frag(bMy, brow0 + 32 + j * 16 + l16, s * 4 + quad);
    if (t + 1 < KT) stage(pAn + 128 * HIDDEN, nb + 8192);   // A(t+1) hi
    __builtin_amdgcn_sched_barrier(0);
    __builtin_amdgcn_s_barrier();
    asm volatile("s_waitcnt lgkmcnt(0)" ::: "memory");
    __builtin_amdgcn_sched_barrier(0);
    __builtin_amdgcn_s_setprio(1);
#pragma unroll
    for (int i = 0; i < 4; ++i)
#pragma unroll
      for (int j = 0; j < 2; ++j)
#pragma unroll
        for (int s = 0; s < 2; ++s)
          acc[i][2 + j] = __builtin_amdgcn_mfma_f32_16x16x32_bf16(af[i][s], bB[j][s], acc[i][2 + j], 0, 0, 0);
    __builtin_amdgcn_s_setprio(0);
    __builtin_amdgcn_sched_barrier(0);
    __builtin_amdgcn_s_barrier();

    // ---------------- P3: quadrant (rows 4-7, cols 2-3) ----------------
#pragma unroll
    for (int i = 0; i < 4; ++i)
#pragma unroll
      for (int s = 0; s < 2; ++s)
        af[i][s] = frag(aMy, 64 + i * 16 + l16, s * 4 + quad);
    if (t + 2 < KT) stage(pBn, b + 16384);          // B(t+2) lo -> current buf (B reads done @P2)
    __builtin_amdgcn_sched_barrier(0);
    __builtin_amdgcn_s_barrier();
    asm volatile("s_waitcnt lgkmcnt(0)" ::: "memory");
    __builtin_amdgcn_sched_barrier(0);
    __builtin_amdgcn_s_setprio(1);
#pragma unroll
    for (int i = 0; i < 4; ++i)
#pragma unroll
      for (int j = 0; j < 2; ++j)
#pragma unroll
        for (int s = 0; s < 2; ++s)
          acc[4 + i][2 + j] = __builtin_amdgcn_mfma_f32_16x16x32_bf16(af[i][s], bB[j][s], acc[4 + i][2 + j], 0, 0, 0);
    __builtin_amdgcn_s_setprio(0);
    __builtin_amdgcn_sched_barrier(0);
    __builtin_amdgcn_s_barrier();

    // ---------------- P4: quadrant (rows 4-7, cols 0-1) ----------------
    if (t + 2 < KT) stage(pBn + 128 * HIDDEN, b + 24576);   // B(t+2) hi
    __builtin_amdgcn_sched_barrier(0);
    __builtin_amdgcn_s_barrier();
    __builtin_amdgcn_s_setprio(1);
#pragma unroll
    for (int i = 0; i < 4; ++i)
#pragma unroll
      for (int j = 0; j < 2; ++j)
#pragma unroll
        for (int s = 0; s < 2; ++s)
          acc[4 + i][j] = __builtin_amdgcn_mfma_f32_16x16x32_bf16(af[i][s], bA[j][s], acc[4 + i][j], 0, 0, 0);
    __builtin_amdgcn_s_setprio(0);
    __builtin_amdgcn_sched_barrier(0);
    // end-of-tile counted wait: leave only B(t+2) halves (4 loads) in flight
    if (t + 2 < KT) asm volatile("s_waitcnt vmcnt(4)" ::: "memory");
    else            asm volatile("s_waitcnt vmcnt(0)" ::: "memory");
    __builtin_amdgcn_s_barrier();
  }

  // ---- epilogue: C/D layout col=lane&15, row=quad*4+reg (m89/m91-verified) ----
  const int rb = yt * 256 + wmh * 128 + quad * 4;
  const int cb = xt * 256 + wnq * 64 + l16;
#pragma unroll
  for (int i = 0; i < 8; ++i) {
#pragma unroll
    for (int r = 0; r < 4; ++r) {
      const int m = rb + i * 16 + r;
      int bidx = 0;
      if (SECOND) bidx = perm[m];
#pragma unroll
      for (int j = 0; j < 4; ++j) {
        const int n = cb + j * 16;
        float v = acc[i][j][r] + bias[e * HIDDEN + n];
        v = v > 0.0f ? v : 0.0f;
        if (SECOND) {
          if (bidx >= 0) Yout[(size_t)bidx * HIDDEN + n] = v;
        } else {
          Hout[(size_t)m * HIDDEN + n] = (short)f2bf(v);
        }
      }
    }
  }
}

extern "C" void kernel_launch(void* const* d_in, const int* in_sizes, int n_in,
                              void* d_out, int out_size, void* d_ws, size_t ws_size,
                              hipStream_t stream) {
  const float* x  = (const float*)d_in[0];
  const float* W1 = (const float*)d_in[1];
  const float* b1 = (const float*)d_in[2];
  const float* W2 = (const float*)d_in[3];
  const float* b2 = (const float*)d_in[4];
  const int* ops  = (const int*)d_in[5];
  float* out = (float*)d_out;

  char* ws = (char*)d_ws;
  short* xb  = (short*)(ws);
  short* h   = (short*)(ws + XB_SZ);
  short* w1t = (short*)(ws + XB_SZ + H_SZ);
  short* w2t = (short*)(ws + XB_SZ + H_SZ + WT_SZ);
  int* perm  = (int*)(ws + XB_SZ + H_SZ + 2 * WT_SZ);
  int* meta  = (int*)(ws + XB_SZ + H_SZ + 2 * WT_SZ + PERM_SZ);
  int* cnt = meta;       // [3]
  int* c2  = meta + 4;   // [3]
  int* seg = meta + 8;   // [4]
  int* te  = meta + 16;  // [NT_M]

  static bool attr_done = false;
  if (!attr_done) {
    hipFuncSetAttribute((const void*)gemm256<0>,
                        hipFuncAttributeMaxDynamicSharedMemorySize, 131072);
    hipFuncSetAttribute((const void*)gemm256<1>,
                        hipFuncAttributeMaxDynamicSharedMemorySize, 131072);
    attr_done = true;
  }

  hipMemsetAsync(meta, 0, 32, stream);
  k_count<<<(M_CAP + 255) / 256, 256, 0, stream>>>(ops, cnt, perm);
  k_scan<<<1, 64, 0, stream>>>(cnt, seg, te);
  k_perm<<<BATCH / 256, 256, 0, stream>>>(ops, seg, c2, perm);
  k_prep<<<M_CAP + 6 * 32 * 32, 256, 0, stream>>>(x, perm, xb, W1, W2, w1t, w2t);
  gemm256<0><<<NXT * NT_M, 512, 131072, stream>>>(xb, w1t, b1, te, perm, h, nullptr);
  gemm256<1><<<NXT * NT_M, 512, 131072, stream>>>(h, w2t, b2, te, perm, nullptr, out);
}